// Round 1
// baseline (981.157 us; speedup 1.0000x reference)
//
#include <hip/hip_runtime.h>
#include <math.h>

#define T_SEQ 1024
#define CM 256
#define HEADS 8
#define DHH 32
#define NB 4

// ---------------------------------------------------------------------------
// K1: qkv = x @ Wqkv, scattered into q,k,v,g with layout [B,H,T,DH].
// Column c of Wqkv decomposes as c = d*32 + kk*8 + h (reshape (DH,4,H)).
// M=4096, N=1024, K=256. 64x64 tile, 256 threads, 4x4 microtile.
// ---------------------------------------------------------------------------
__global__ __launch_bounds__(256) void qkv_gemm(const float* __restrict__ x,
                                                const float* __restrict__ Wqkv,
                                                float* __restrict__ q,
                                                float* __restrict__ kptr,
                                                float* __restrict__ v,
                                                float* __restrict__ g) {
    __shared__ float As[16][68];   // [k][m], padded
    __shared__ float Bs[16][64];   // [k][n]
    const int tid = threadIdx.x;
    const int tx = tid & 15, ty = tid >> 4;
    const int m0 = blockIdx.y * 64;
    const int n0 = blockIdx.x * 64;
    float acc[4][4] = {};
    for (int k0 = 0; k0 < 256; k0 += 16) {
        __syncthreads();
        {   // A tile: x[m0..+63][k0..+15], transposed into As[k][m]
            int r = tid >> 2;            // 0..63
            int c4 = (tid & 3) * 4;      // 0,4,8,12
            const float4 a4 = *(const float4*)&x[(m0 + r) * 256 + k0 + c4];
            As[c4 + 0][r] = a4.x; As[c4 + 1][r] = a4.y;
            As[c4 + 2][r] = a4.z; As[c4 + 3][r] = a4.w;
        }
        {   // B tile: Wqkv[k0..+15][n0..+63]
            int kr = tid >> 4;           // 0..15
            int c4 = (tid & 15) * 4;     // 0..60
            *(float4*)&Bs[kr][c4] = *(const float4*)&Wqkv[(k0 + kr) * 1024 + n0 + c4];
        }
        __syncthreads();
        #pragma unroll
        for (int kk = 0; kk < 16; ++kk) {
            float4 a4 = *(const float4*)&As[kk][ty * 4];
            float a[4] = {a4.x, a4.y, a4.z, a4.w};
            float b[4];
            #pragma unroll
            for (int cc = 0; cc < 4; ++cc) b[cc] = Bs[kk][tx + 16 * cc];
            #pragma unroll
            for (int rr = 0; rr < 4; ++rr)
                #pragma unroll
                for (int cc = 0; cc < 4; ++cc)
                    acc[rr][cc] += a[rr] * b[cc];
        }
    }
    #pragma unroll
    for (int rr = 0; rr < 4; ++rr) {
        int row = m0 + ty * 4 + rr;
        int b = row >> 10, t = row & 1023;
        #pragma unroll
        for (int cc = 0; cc < 4; ++cc) {
            int c = n0 + tx + 16 * cc;
            int d = c >> 5, kk4 = (c >> 3) & 3, h = c & 7;
            float* dst = (kk4 == 0) ? q : (kk4 == 1) ? kptr : (kk4 == 2) ? v : g;
            dst[((b * HEADS + h) * T_SEQ + t) * DHH + d] = acc[rr][cc];
        }
    }
}

// ---------------------------------------------------------------------------
// K2: pb[h][i][j] = bias_rep[i][j][:] . Wb[:][h] + bb[h].   (512 MB read)
// 32 lanes per (i,j) pair, float4 loads; 64 pairs per block; staged writes.
// ---------------------------------------------------------------------------
__global__ __launch_bounds__(256) void pair_bias_kernel(const float* __restrict__ bias_rep,
                                                        const float* __restrict__ Wb,
                                                        const float* __restrict__ bb,
                                                        float* __restrict__ pb) {
    __shared__ float wLds[8 * 128];     // transposed: wLds[h*128 + c]
    __shared__ float outLds[8][64];
    const int tid = threadIdx.x;
    for (int idx = tid; idx < 1024; idx += 256) {
        int c = idx & 127, h = idx >> 7;
        wLds[h * 128 + c] = Wb[c * 8 + h];
    }
    __syncthreads();
    const int group = tid >> 5;        // 0..7
    const int lane32 = tid & 31;
    const int cbase = lane32 * 4;
    const long long p0 = (long long)blockIdx.x * 64;
    for (int it = 0; it < 8; ++it) {
        long long p = p0 + it * 8 + group;
        float4 bv = *(const float4*)&bias_rep[p * 128 + cbase];
        float acc[8];
        #pragma unroll
        for (int h = 0; h < 8; ++h) {
            float4 w = *(const float4*)&wLds[h * 128 + cbase];
            acc[h] = bv.x * w.x + bv.y * w.y + bv.z * w.z + bv.w * w.w;
        }
        #pragma unroll
        for (int off = 16; off >= 1; off >>= 1)
            #pragma unroll
            for (int h = 0; h < 8; ++h)
                acc[h] += __shfl_xor(acc[h], off);
        if (lane32 == 0)
            #pragma unroll
            for (int h = 0; h < 8; ++h)
                outLds[h][it * 8 + group] = acc[h] + bb[h];
    }
    __syncthreads();
    for (int idx = tid; idx < 512; idx += 256) {
        int h = idx >> 6, pp = idx & 63;
        pb[(long long)h * (T_SEQ * T_SEQ) + p0 + pp] = outLds[h][pp];
    }
}

// ---------------------------------------------------------------------------
// K3: flash attention per (b, h, 64-row Q tile). fp32, online softmax.
// Produces gated[b*T + t][h*32 + d] = (softmax(QK^T*scale + pb) V) * sigmoid(g)
// ---------------------------------------------------------------------------
__global__ __launch_bounds__(256) void attn_kernel(const float* __restrict__ q,
                                                   const float* __restrict__ k,
                                                   const float* __restrict__ v,
                                                   const float* __restrict__ g,
                                                   const float* __restrict__ pb,
                                                   float* __restrict__ gated) {
    __shared__ float Qs[64][36];   // padded stride 36: conflict-light, 16B-aligned rows
    __shared__ float Ks[64][36];
    __shared__ float Vs[64][36];
    __shared__ float Ss[64][68];   // S/P tile + bias staging; stride 68 (16B-aligned)
    __shared__ float m_s[64], l_s[64], alpha_s[64];
    const int tid = threadIdx.x;
    const int tx = tid & 15, ty = tid >> 4;
    const int it0 = blockIdx.x * 64;
    const int h = blockIdx.y, b = blockIdx.z;
    const float scale = 0.17677669529663687f;  // 32^-0.5
    const long long qoff = ((long long)(b * HEADS + h) * T_SEQ) * DHH;
    // load Q tile (pre-scaled)
    for (int f4 = tid; f4 < 512; f4 += 256) {
        int r = f4 >> 3, dd = (f4 & 7) * 4;
        float4 qv = *(const float4*)&q[qoff + (long long)(it0 + r) * DHH + dd];
        qv.x *= scale; qv.y *= scale; qv.z *= scale; qv.w *= scale;
        *(float4*)&Qs[r][dd] = qv;
    }
    if (tid < 64) { m_s[tid] = -INFINITY; l_s[tid] = 0.f; }
    float O[4][2] = {};
    const long long pboff = (long long)h * (T_SEQ * T_SEQ) + (long long)it0 * T_SEQ;

    for (int jt = 0; jt < 16; ++jt) {
        int j0 = jt * 64;
        __syncthreads();   // protect Ks/Vs/Ss reuse from previous PV
        for (int f4 = tid; f4 < 512; f4 += 256) {
            int r = f4 >> 3, dd = (f4 & 7) * 4;
            *(float4*)&Ks[r][dd] = *(const float4*)&k[qoff + (long long)(j0 + r) * DHH + dd];
            *(float4*)&Vs[r][dd] = *(const float4*)&v[qoff + (long long)(j0 + r) * DHH + dd];
        }
        for (int f4 = tid; f4 < 1024; f4 += 256) {
            int r = f4 >> 4, cc = (f4 & 15) * 4;
            *(float4*)&Ss[r][cc] = *(const float4*)&pb[pboff + (long long)r * T_SEQ + j0 + cc];
        }
        __syncthreads();
        // S microtile: rows ty*4+rr, cols tx+16*cc
        float s[4][4] = {};
        #pragma unroll
        for (int kk = 0; kk < 32; kk += 4) {
            float4 qv[4], kv[4];
            #pragma unroll
            for (int rr = 0; rr < 4; ++rr) qv[rr] = *(const float4*)&Qs[ty * 4 + rr][kk];
            #pragma unroll
            for (int cc = 0; cc < 4; ++cc) kv[cc] = *(const float4*)&Ks[tx + 16 * cc][kk];
            #pragma unroll
            for (int rr = 0; rr < 4; ++rr)
                #pragma unroll
                for (int cc = 0; cc < 4; ++cc)
                    s[rr][cc] += qv[rr].x * kv[cc].x + qv[rr].y * kv[cc].y +
                                 qv[rr].z * kv[cc].z + qv[rr].w * kv[cc].w;
        }
        // add bias (already in Ss), write back full logits
        #pragma unroll
        for (int rr = 0; rr < 4; ++rr)
            #pragma unroll
            for (int cc = 0; cc < 4; ++cc) {
                int i = ty * 4 + rr, j = tx + 16 * cc;
                Ss[i][j] = s[rr][cc] + Ss[i][j];
            }
        __syncthreads();
        // online softmax: one thread per row
        if (tid < 64) {
            int i = tid;
            float mold = m_s[i];
            float mnew = mold;
            for (int j = 0; j < 64; j += 4) {
                float4 sv = *(const float4*)&Ss[i][j];
                mnew = fmaxf(mnew, fmaxf(fmaxf(sv.x, sv.y), fmaxf(sv.z, sv.w)));
            }
            float alpha = __expf(mold - mnew);
            float sum = 0.f;
            for (int j = 0; j < 64; j += 4) {
                float4 sv = *(const float4*)&Ss[i][j];
                sv.x = __expf(sv.x - mnew); sv.y = __expf(sv.y - mnew);
                sv.z = __expf(sv.z - mnew); sv.w = __expf(sv.w - mnew);
                sum += sv.x + sv.y + sv.z + sv.w;
                *(float4*)&Ss[i][j] = sv;
            }
            m_s[i] = mnew;
            l_s[i] = l_s[i] * alpha + sum;
            alpha_s[i] = alpha;
        }
        __syncthreads();
        // rescale O and accumulate P @ V. O rows ty*4+rr, cols d = 2*tx, 2*tx+1
        #pragma unroll
        for (int rr = 0; rr < 4; ++rr) {
            float al = alpha_s[ty * 4 + rr];
            O[rr][0] *= al; O[rr][1] *= al;
        }
        for (int j = 0; j < 64; ++j) {
            float2 vv = *(const float2*)&Vs[j][tx * 2];
            #pragma unroll
            for (int rr = 0; rr < 4; ++rr) {
                float p = Ss[ty * 4 + rr][j];
                O[rr][0] += p * vv.x;
                O[rr][1] += p * vv.y;
            }
        }
    }
    // epilogue: divide by l, gate with sigmoid(g), store to [b*T+t][h*32+d]
    #pragma unroll
    for (int rr = 0; rr < 4; ++rr) {
        int i = ty * 4 + rr;
        float linv = 1.f / l_s[i];
        float2 gv = *(const float2*)&g[qoff + (long long)(it0 + i) * DHH + tx * 2];
        float s0 = 1.f / (1.f + __expf(-gv.x));
        float s1 = 1.f / (1.f + __expf(-gv.y));
        float o0 = O[rr][0] * linv * s0;
        float o1 = O[rr][1] * linv * s1;
        long long orow = ((long long)b * T_SEQ + it0 + i) * CM + h * DHH + tx * 2;
        *(float2*)&gated[orow] = make_float2(o0, o1);
    }
}

// ---------------------------------------------------------------------------
// K4: y = gated @ W0.  M=4096, N=256, K=256.
// ---------------------------------------------------------------------------
__global__ __launch_bounds__(256) void out_gemm(const float* __restrict__ A,
                                                const float* __restrict__ W0,
                                                float* __restrict__ y) {
    __shared__ float As[16][68];
    __shared__ float Bs[16][64];
    const int tid = threadIdx.x;
    const int tx = tid & 15, ty = tid >> 4;
    const int m0 = blockIdx.y * 64;
    const int n0 = blockIdx.x * 64;
    float acc[4][4] = {};
    for (int k0 = 0; k0 < 256; k0 += 16) {
        __syncthreads();
        {
            int r = tid >> 2;
            int c4 = (tid & 3) * 4;
            const float4 a4 = *(const float4*)&A[(m0 + r) * 256 + k0 + c4];
            As[c4 + 0][r] = a4.x; As[c4 + 1][r] = a4.y;
            As[c4 + 2][r] = a4.z; As[c4 + 3][r] = a4.w;
        }
        {
            int kr = tid >> 4;
            int c4 = (tid & 15) * 4;
            *(float4*)&Bs[kr][c4] = *(const float4*)&W0[(k0 + kr) * 256 + n0 + c4];
        }
        __syncthreads();
        #pragma unroll
        for (int kk = 0; kk < 16; ++kk) {
            float4 a4 = *(const float4*)&As[kk][ty * 4];
            float a[4] = {a4.x, a4.y, a4.z, a4.w};
            float b[4];
            #pragma unroll
            for (int cc = 0; cc < 4; ++cc) b[cc] = Bs[kk][tx + 16 * cc];
            #pragma unroll
            for (int rr = 0; rr < 4; ++rr)
                #pragma unroll
                for (int cc = 0; cc < 4; ++cc)
                    acc[rr][cc] += a[rr] * b[cc];
        }
    }
    #pragma unroll
    for (int rr = 0; rr < 4; ++rr)
        #pragma unroll
        for (int cc = 0; cc < 4; ++cc)
            y[(m0 + ty * 4 + rr) * 256 + n0 + tx + 16 * cc] = acc[rr][cc];
}

// ---------------------------------------------------------------------------
extern "C" void kernel_launch(void* const* d_in, const int* in_sizes, int n_in,
                              void* d_out, int out_size, void* d_ws, size_t ws_size,
                              hipStream_t stream) {
    const float* x        = (const float*)d_in[0];   // [4,1024,256]
    const float* bias_rep = (const float*)d_in[1];   // [1024,1024,128]
    const float* Wqkv     = (const float*)d_in[2];   // [256,1024]
    const float* W0       = (const float*)d_in[3];   // [256,256]
    const float* Wb       = (const float*)d_in[4];   // [128,8]
    const float* bb       = (const float*)d_in[5];   // [8]
    float* ws = (float*)d_ws;

    const size_t SZ_BHTD = (size_t)NB * HEADS * T_SEQ * DHH;     // 1,048,576
    float* q     = ws;
    float* k     = ws + SZ_BHTD;
    float* v     = ws + 2 * SZ_BHTD;
    float* g     = ws + 3 * SZ_BHTD;
    float* pb    = ws + 4 * SZ_BHTD;                              // [8][1024][1024]
    float* gated = pb + (size_t)HEADS * T_SEQ * T_SEQ;            // [4096][256]
    float* y     = (float*)d_out;

    qkv_gemm<<<dim3(16, 64), 256, 0, stream>>>(x, Wqkv, q, k, v, g);
    pair_bias_kernel<<<dim3(16384), 256, 0, stream>>>(bias_rep, Wb, bb, pb);
    attn_kernel<<<dim3(16, 8, 4), 256, 0, stream>>>(q, k, v, g, pb, gated);
    out_gemm<<<dim3(4, 64), 256, 0, stream>>>(gated, W0, y);
}

// Round 2
// 884.665 us; speedup vs baseline: 1.1091x; 1.1091x over previous
//
#include <hip/hip_runtime.h>
#include <math.h>

#define T_SEQ 1024
#define CM 256
#define HEADS 8
#define DHH 32
#define NB 4

typedef __attribute__((ext_vector_type(8))) short bf16x8;
typedef __attribute__((ext_vector_type(4))) float f32x4;

__device__ __forceinline__ unsigned short f2bf(float f) {
    unsigned u = __builtin_bit_cast(unsigned, f);
    unsigned r = (u + 0x7FFFu + ((u >> 16) & 1u)) >> 16;
    return (unsigned short)r;
}

// ---------------------------------------------------------------------------
// Cast kernels (one-time, off critical path)
// ---------------------------------------------------------------------------
__global__ __launch_bounds__(256) void cast_x_kernel(const float* __restrict__ x,
                                                     unsigned short* __restrict__ xb) {
    int i = blockIdx.x * 256 + threadIdx.x;      // 262144 threads, 4 elems each
    float4 v = *(const float4*)&x[i * 4];
    ushort4 o;
    o.x = f2bf(v.x); o.y = f2bf(v.y); o.z = f2bf(v.z); o.w = f2bf(v.w);
    *(ushort4*)&xb[i * 4] = o;
}

// Wt[n][k] = W[k][n], K fixed at 256. Output-coalesced bf16 writes.
__global__ __launch_bounds__(256) void transpose_cast_kernel(const float* __restrict__ W,
                                                             unsigned short* __restrict__ Wt,
                                                             int cols) {
    int o = blockIdx.x * 256 + threadIdx.x;
    int n = o >> 8, k = o & 255;
    Wt[o] = f2bf(W[k * cols + n]);
}

// ---------------------------------------------------------------------------
// K1: qkv = x @ Wqkv via bf16 MFMA.  Column c = d*32 + kk*8 + h.
// Virtual col ordering: subtile s -> (h = hbase+(s>>3), kk=(s>>1)&3, dhi=s&1),
// lane col dlo = lane&15, real col = (dhi*16+dlo)*32 + kk*8 + h.
// Each wave: 16 rows x 256 vcols (2 heads). Grid (4 h-pairs, 64 m-tiles).
// q pre-scaled by DH^-0.5; v written transposed [B,H,DH,T].
// ---------------------------------------------------------------------------
__global__ __launch_bounds__(256) void qkv_gemm_mfma(const unsigned short* __restrict__ xb,
                                                     const unsigned short* __restrict__ Wt,
                                                     unsigned short* __restrict__ qb,
                                                     unsigned short* __restrict__ kb,
                                                     unsigned short* __restrict__ vT,
                                                     float* __restrict__ g) {
    const int tid = threadIdx.x;
    const int w = tid >> 6;
    const int lane = tid & 63;
    const int n16 = lane & 15;
    const int quad = lane >> 4;
    const int m0 = blockIdx.y * 64 + w * 16;
    const int hbase = blockIdx.x * 2;
    const float scale = 0.17677669529663687f;

    bf16x8 afr[8];
    #pragma unroll
    for (int kc = 0; kc < 8; ++kc)
        afr[kc] = *(const bf16x8*)&xb[(m0 + n16) * 256 + kc * 32 + quad * 8];

    #pragma unroll
    for (int s = 0; s < 16; ++s) {
        const int h = hbase + (s >> 3);
        const int kk = (s >> 1) & 3;
        const int dhi = s & 1;
        const int c = (dhi * 16 + n16) * 32 + kk * 8 + h;
        f32x4 acc = {0.f, 0.f, 0.f, 0.f};
        #pragma unroll
        for (int kc = 0; kc < 8; ++kc) {
            bf16x8 bfr = *(const bf16x8*)&Wt[c * 256 + kc * 32 + quad * 8];
            acc = __builtin_amdgcn_mfma_f32_16x16x32_bf16(afr[kc], bfr, acc, 0, 0, 0);
        }
        const int d = dhi * 16 + n16;
        #pragma unroll
        for (int r = 0; r < 4; ++r) {
            int m = m0 + quad * 4 + r;
            int b = m >> 10, t = m & 1023;
            int bh = b * HEADS + h;
            float val = acc[r];
            if (kk == 0)      qb[(bh * T_SEQ + t) * DHH + d] = f2bf(val * scale);
            else if (kk == 1) kb[(bh * T_SEQ + t) * DHH + d] = f2bf(val);
            else if (kk == 2) vT[(bh * DHH + d) * T_SEQ + t] = f2bf(val);
            else              g[(bh * T_SEQ + t) * DHH + d] = val;
        }
    }
}

// ---------------------------------------------------------------------------
// K2: pb[h][i][j] = bias_rep[i][j][:] . Wb[:][h] + bb[h].   (512 MB read)
// ---------------------------------------------------------------------------
__global__ __launch_bounds__(256) void pair_bias_kernel(const float* __restrict__ bias_rep,
                                                        const float* __restrict__ Wb,
                                                        const float* __restrict__ bb,
                                                        float* __restrict__ pb) {
    __shared__ float wLds[8 * 128];
    __shared__ float outLds[8][64];
    const int tid = threadIdx.x;
    for (int idx = tid; idx < 1024; idx += 256) {
        int c = idx & 127, h = idx >> 7;
        wLds[h * 128 + c] = Wb[c * 8 + h];
    }
    __syncthreads();
    const int group = tid >> 5;
    const int lane32 = tid & 31;
    const int cbase = lane32 * 4;
    const long long p0 = (long long)blockIdx.x * 64;
    for (int it = 0; it < 8; ++it) {
        long long p = p0 + it * 8 + group;
        float4 bv = *(const float4*)&bias_rep[p * 128 + cbase];
        float acc[8];
        #pragma unroll
        for (int h = 0; h < 8; ++h) {
            float4 ww = *(const float4*)&wLds[h * 128 + cbase];
            acc[h] = bv.x * ww.x + bv.y * ww.y + bv.z * ww.z + bv.w * ww.w;
        }
        #pragma unroll
        for (int off = 16; off >= 1; off >>= 1)
            #pragma unroll
            for (int h = 0; h < 8; ++h)
                acc[h] += __shfl_xor(acc[h], off);
        if (lane32 == 0)
            #pragma unroll
            for (int h = 0; h < 8; ++h)
                outLds[h][it * 8 + group] = acc[h] + bb[h];
    }
    __syncthreads();
    for (int idx = tid; idx < 512; idx += 256) {
        int h = idx >> 6, pp = idx & 63;
        pb[(long long)h * (T_SEQ * T_SEQ) + p0 + pp] = outLds[h][pp];
    }
}

// ---------------------------------------------------------------------------
// K3: flash attention, bf16 MFMA, barrier-free (each wave owns 16 Q rows).
// Q A-frag + K B-frags direct from global (coalesced by construction);
// V B-frags from transposed vT; P round-trips through a per-wave LDS strip.
// Softmax state (m,l) in registers, reduced across 16-lane C-layout groups.
// ---------------------------------------------------------------------------
__global__ __launch_bounds__(256) void attn_mfma(const unsigned short* __restrict__ qb,
                                                 const unsigned short* __restrict__ kb,
                                                 const unsigned short* __restrict__ vT,
                                                 const float* __restrict__ g,
                                                 const float* __restrict__ pb,
                                                 unsigned short* __restrict__ gated) {
    __shared__ unsigned short Ps[4][16][72];   // per-wave 16x64 strip, pad->2-way max
    const int tid = threadIdx.x;
    const int w = tid >> 6;
    const int lane = tid & 63;
    const int n16 = lane & 15;
    const int quad = lane >> 4;
    const int it0 = blockIdx.x * 64;
    const int h = blockIdx.y, b = blockIdx.z;
    const int bh = b * HEADS + h;
    const int qrow0 = it0 + w * 16;

    bf16x8 qfr = *(const bf16x8*)&qb[(bh * T_SEQ + qrow0 + n16) * DHH + quad * 8];

    float m_i[4] = {-INFINITY, -INFINITY, -INFINITY, -INFINITY};
    float l_i[4] = {0.f, 0.f, 0.f, 0.f};
    f32x4 O0 = {0.f, 0.f, 0.f, 0.f};
    f32x4 O1 = {0.f, 0.f, 0.f, 0.f};

    for (int jt = 0; jt < 16; ++jt) {
        const int j0 = jt * 64;
        f32x4 S[4];
        #pragma unroll
        for (int s4 = 0; s4 < 4; ++s4) {
            bf16x8 kfr = *(const bf16x8*)&kb[(bh * T_SEQ + j0 + s4 * 16 + n16) * DHH + quad * 8];
            f32x4 z = {0.f, 0.f, 0.f, 0.f};
            S[s4] = __builtin_amdgcn_mfma_f32_16x16x32_bf16(qfr, kfr, z, 0, 0, 0);
        }
        // add pair bias (C-layout: row = quad*4+r, col = s4*16+n16)
        #pragma unroll
        for (int s4 = 0; s4 < 4; ++s4)
            #pragma unroll
            for (int r = 0; r < 4; ++r)
                S[s4][r] += pb[h * (T_SEQ * T_SEQ) + (qrow0 + quad * 4 + r) * T_SEQ + j0 + s4 * 16 + n16];
        // online softmax, all in registers
        #pragma unroll
        for (int r = 0; r < 4; ++r) {
            float mx = fmaxf(fmaxf(S[0][r], S[1][r]), fmaxf(S[2][r], S[3][r]));
            mx = fmaxf(mx, __shfl_xor(mx, 1));
            mx = fmaxf(mx, __shfl_xor(mx, 2));
            mx = fmaxf(mx, __shfl_xor(mx, 4));
            mx = fmaxf(mx, __shfl_xor(mx, 8));
            float mnew = fmaxf(m_i[r], mx);
            float alpha = __expf(m_i[r] - mnew);
            m_i[r] = mnew;
            float sum = 0.f;
            #pragma unroll
            for (int s4 = 0; s4 < 4; ++s4) {
                float p = __expf(S[s4][r] - mnew);
                S[s4][r] = p;
                sum += p;
            }
            sum += __shfl_xor(sum, 1);
            sum += __shfl_xor(sum, 2);
            sum += __shfl_xor(sum, 4);
            sum += __shfl_xor(sum, 8);
            l_i[r] = l_i[r] * alpha + sum;
            O0[r] *= alpha;
            O1[r] *= alpha;
        }
        // P: C-layout -> LDS -> A-layout (per-wave strip, no barrier needed)
        #pragma unroll
        for (int s4 = 0; s4 < 4; ++s4)
            #pragma unroll
            for (int r = 0; r < 4; ++r)
                Ps[w][quad * 4 + r][s4 * 16 + n16] = f2bf(S[s4][r]);
        #pragma unroll
        for (int kc = 0; kc < 2; ++kc) {
            bf16x8 pfr = *(const bf16x8*)&Ps[w][n16][kc * 32 + quad * 8];
            bf16x8 v0 = *(const bf16x8*)&vT[(bh * DHH + n16) * T_SEQ + j0 + kc * 32 + quad * 8];
            bf16x8 v1 = *(const bf16x8*)&vT[(bh * DHH + 16 + n16) * T_SEQ + j0 + kc * 32 + quad * 8];
            O0 = __builtin_amdgcn_mfma_f32_16x16x32_bf16(pfr, v0, O0, 0, 0, 0);
            O1 = __builtin_amdgcn_mfma_f32_16x16x32_bf16(pfr, v1, O1, 0, 0, 0);
        }
    }
    // epilogue: 1/l, sigmoid gate, bf16 store to gated[b*T+t][h*32+d]
    #pragma unroll
    for (int r = 0; r < 4; ++r) {
        int t = qrow0 + quad * 4 + r;
        float linv = 1.f / l_i[r];
        float g0 = g[(bh * T_SEQ + t) * DHH + n16];
        float g1 = g[(bh * T_SEQ + t) * DHH + 16 + n16];
        float o0 = O0[r] * linv / (1.f + __expf(-g0));
        float o1 = O1[r] * linv / (1.f + __expf(-g1));
        gated[(b * T_SEQ + t) * CM + h * DHH + n16] = f2bf(o0);
        gated[(b * T_SEQ + t) * CM + h * DHH + 16 + n16] = f2bf(o1);
    }
}

// ---------------------------------------------------------------------------
// K4: y = gated @ W0 via bf16 MFMA. 1 wave/block, 16 rows x 256 cols.
// ---------------------------------------------------------------------------
__global__ __launch_bounds__(64) void out_gemm_mfma(const unsigned short* __restrict__ gb,
                                                    const unsigned short* __restrict__ W0t,
                                                    float* __restrict__ y) {
    const int lane = threadIdx.x;
    const int n16 = lane & 15;
    const int quad = lane >> 4;
    const int m0 = blockIdx.x * 16;

    bf16x8 afr[8];
    #pragma unroll
    for (int kc = 0; kc < 8; ++kc)
        afr[kc] = *(const bf16x8*)&gb[(m0 + n16) * 256 + kc * 32 + quad * 8];

    #pragma unroll
    for (int s = 0; s < 16; ++s) {
        f32x4 acc = {0.f, 0.f, 0.f, 0.f};
        #pragma unroll
        for (int kc = 0; kc < 8; ++kc) {
            bf16x8 bfr = *(const bf16x8*)&W0t[(s * 16 + n16) * 256 + kc * 32 + quad * 8];
            acc = __builtin_amdgcn_mfma_f32_16x16x32_bf16(afr[kc], bfr, acc, 0, 0, 0);
        }
        #pragma unroll
        for (int r = 0; r < 4; ++r)
            y[(m0 + quad * 4 + r) * 256 + s * 16 + n16] = acc[r];
    }
}

// ---------------------------------------------------------------------------
extern "C" void kernel_launch(void* const* d_in, const int* in_sizes, int n_in,
                              void* d_out, int out_size, void* d_ws, size_t ws_size,
                              hipStream_t stream) {
    const float* x        = (const float*)d_in[0];   // [4,1024,256]
    const float* bias_rep = (const float*)d_in[1];   // [1024,1024,128]
    const float* Wqkv     = (const float*)d_in[2];   // [256,1024]
    const float* W0       = (const float*)d_in[3];   // [256,256]
    const float* Wb       = (const float*)d_in[4];   // [128,8]
    const float* bb       = (const float*)d_in[5];   // [8]

    char* ws = (char*)d_ws;
    float*          pb    = (float*)ws;                 ws += 8LL * 1024 * 1024 * 4;  // 32 MB
    float*          g     = (float*)ws;                 ws += 4LL * 1024 * 1024;      // 4 MB
    unsigned short* qb    = (unsigned short*)ws;        ws += 2LL * 1024 * 1024;      // 2 MB
    unsigned short* kb    = (unsigned short*)ws;        ws += 2LL * 1024 * 1024;
    unsigned short* vT    = (unsigned short*)ws;        ws += 2LL * 1024 * 1024;
    unsigned short* gated = (unsigned short*)ws;        ws += 2LL * 1024 * 1024;
    unsigned short* xb    = (unsigned short*)ws;        ws += 2LL * 1024 * 1024;
    unsigned short* Wt    = (unsigned short*)ws;        ws += 512LL * 1024;
    unsigned short* W0t   = (unsigned short*)ws;
    float* y = (float*)d_out;

    cast_x_kernel<<<1024, 256, 0, stream>>>(x, xb);
    transpose_cast_kernel<<<1024, 256, 0, stream>>>(Wqkv, Wt, 1024);
    transpose_cast_kernel<<<256, 256, 0, stream>>>(W0, W0t, 256);
    qkv_gemm_mfma<<<dim3(4, 64), 256, 0, stream>>>(xb, Wt, qb, kb, vT, g);
    pair_bias_kernel<<<dim3(16384), 256, 0, stream>>>(bias_rep, Wb, bb, pb);
    attn_mfma<<<dim3(16, HEADS, NB), 256, 0, stream>>>(qb, kb, vT, g, pb, gated);
    out_gemm_mfma<<<256, 64, 0, stream>>>(gated, W0t, y);
}